// Round 1
// baseline (320.976 us; speedup 1.0000x reference)
//
#include <hip/hip_runtime.h>

// BAD descriptor: integral image + clamped box-mean differences.
// B=2, H=W=224, P=256, max_radius=3.
#define BN 2
#define HN 224
#define WN 224
#define PN 256
#define RN 3
#define IW 231          // H + 2*R + 1  (integral has a zero top row / left col)
#define ISZ (IW * IW)

__global__ __launch_bounds__(256) void row_cumsum_kernel(
    const float* __restrict__ x, float* __restrict__ I)
{
    int t = blockIdx.x * 256 + threadIdx.x;
    if (t >= BN * IW) return;
    int b = t / IW, i = t % IW;
    float* Ib = I + b * ISZ + i * IW;
    if (i == 0) {
        // zero top row
        for (int j = 0; j < IW; ++j) Ib[j] = 0.0f;
        return;
    }
    // padded row i-1 maps to source row clamp(i-1-R, 0, H-1) (replicate pad)
    int yy = i - 1 - RN;
    yy = yy < 0 ? 0 : (yy > HN - 1 ? HN - 1 : yy);
    const float* xr = x + b * HN * WN + yy * WN;
    Ib[0] = 0.0f;
    float acc = 0.0f;
#pragma unroll 10
    for (int j = 1; j < IW; ++j) {
        int xx = j - 1 - RN;
        xx = xx < 0 ? 0 : (xx > WN - 1 ? WN - 1 : xx);
        acc += xr[xx];
        Ib[j] = acc;
    }
}

__global__ __launch_bounds__(256) void col_cumsum_kernel(float* __restrict__ I)
{
    int t = blockIdx.x * 256 + threadIdx.x;
    if (t >= BN * IW) return;
    int b = t / IW, j = t % IW;
    float* Ib = I + b * ISZ;
    float acc = 0.0f;
#pragma unroll 10
    for (int i = 1; i < IW; ++i) {
        acc += Ib[i * IW + j];
        Ib[i * IW + j] = acc;
    }
}

__global__ __launch_bounds__(256) void bad_main_kernel(
    const float* __restrict__ I,
    const float* __restrict__ ox1, const float* __restrict__ ox2,
    const float* __restrict__ oy1, const float* __restrict__ oy2,
    const int*   __restrict__ radii, const float* __restrict__ thr,
    float4* __restrict__ out)
{
    const int p = blockIdx.y;
    const int b = blockIdx.z;
    const int g = blockIdx.x * 256 + threadIdx.x;   // 0..12543  (49*256 == 224*224/4 exactly)
    const int y  = g / 56;                           // 56 float4 groups per row
    const int x0 = (g - y * 56) * 4;

    // block-uniform descriptor params -> scalar loads
    const float offx1 = ox1[p], offx2 = ox2[p];
    const float offy1 = oy1[p], offy2 = oy2[p];
    const int   rad   = radii[p];
    const float t     = thr[p];
    const float side  = (float)(2 * rad + 1);
    const float inv_area = 1.0f / (side * side);

    const float* Ib = I + b * ISZ;

    // y terms: fixed per thread
    const float fyf = (float)y;
    float fy1 = fminf(fmaxf(fyf + offy1, 0.0f), (float)(HN - 1));
    int   cy1 = (int)fy1 + RN;
    const float* r1lo = Ib + (cy1 - rad) * IW;
    const float* r1hi = Ib + (cy1 + rad + 1) * IW;
    float fy2 = fminf(fmaxf(fyf + offy2, 0.0f), (float)(HN - 1));
    int   cy2 = (int)fy2 + RN;
    const float* r2lo = Ib + (cy2 - rad) * IW;
    const float* r2hi = Ib + (cy2 + rad + 1) * IW;

    const float fxb = (float)x0;

    float4 res;
    float* resp = (float*)&res;
#pragma unroll
    for (int k = 0; k < 4; ++k) {
        const float fx = fxb + (float)k;             // exact small-int float add

        float fx1 = fminf(fmaxf(fx + offx1, 0.0f), (float)(WN - 1));
        int   cx1 = (int)fx1 + RN;
        int   a0 = cx1 - rad, a1 = cx1 + rad + 1;
        float s1 = r1hi[a1] - r1lo[a1] - r1hi[a0] + r1lo[a0];

        float fx2 = fminf(fmaxf(fx + offx2, 0.0f), (float)(WN - 1));
        int   cx2 = (int)fx2 + RN;
        int   b0 = cx2 - rad, b1 = cx2 + rad + 1;
        float s2 = r2hi[b1] - r2lo[b1] - r2hi[b0] + r2lo[b0];

        resp[k] = s1 * inv_area - s2 * inv_area - t;
    }

    out[(b * PN + p) * (HN * WN / 4) + g] = res;
}

extern "C" void kernel_launch(void* const* d_in, const int* in_sizes, int n_in,
                              void* d_out, int out_size, void* d_ws, size_t ws_size,
                              hipStream_t stream)
{
    const float* x    = (const float*)d_in[0];
    const float* ox1  = (const float*)d_in[1];
    const float* ox2  = (const float*)d_in[2];
    const float* oy1  = (const float*)d_in[3];
    const float* oy2  = (const float*)d_in[4];
    const int*   rad  = (const int*)d_in[5];
    const float* thr  = (const float*)d_in[6];
    // d_in[7] = max_radius (hard-coded RN=3)

    float* I   = (float*)d_ws;            // BN*ISZ floats = ~427 KB
    float4* out = (float4*)d_out;

    hipLaunchKernelGGL(row_cumsum_kernel, dim3((BN * IW + 255) / 256), dim3(256), 0, stream, x, I);
    hipLaunchKernelGGL(col_cumsum_kernel, dim3((BN * IW + 255) / 256), dim3(256), 0, stream, I);
    hipLaunchKernelGGL(bad_main_kernel,   dim3(49, PN, BN), dim3(256), 0, stream,
                       I, ox1, ox2, oy1, oy2, rad, thr, out);
}

// Round 2
// 177.176 us; speedup vs baseline: 1.8116x; 1.8116x over previous
//
#include <hip/hip_runtime.h>

// BAD descriptor: integral image + clamped box-mean differences.
// B=2, H=W=224, P=256, max_radius=3.
#define BN 2
#define HN 224
#define WN 224
#define PN 256
#define RN 3
#define IW 231          // H + 2*R + 1  (integral has a zero top row / left col)
#define ISZ (IW * IW)
#define NPIX (HN * WN)  // 50176 = 196 * 256

// One wave per integral row (wave-shuffle inclusive scan over 4 chunks of 64).
__global__ __launch_bounds__(256) void integral_rows_kernel(
    const float* __restrict__ x, float* __restrict__ I)
{
    const int wave = (blockIdx.x * 256 + threadIdx.x) >> 6;
    const int lane = threadIdx.x & 63;
    if (wave >= BN * IW) return;
    const int b = wave / IW, i = wave % IW;
    float* Ib = I + b * ISZ + i * IW;
    if (i == 0) {   // zero top row
        for (int j = lane; j < IW; j += 64) Ib[j] = 0.0f;
        return;
    }
    int yy = i - 1 - RN;
    yy = yy < 0 ? 0 : (yy > HN - 1 ? HN - 1 : yy);
    const float* xr = x + b * HN * WN + yy * WN;

    float carry = 0.0f;
#pragma unroll
    for (int c = 0; c < 4; ++c) {           // 4*64 = 256 >= 231
        const int j = c * 64 + lane;
        float v = 0.0f;
        if (j >= 1 && j < IW) {
            int xx = j - 1 - RN;
            xx = xx < 0 ? 0 : (xx > WN - 1 ? WN - 1 : xx);
            v = xr[xx];
        }
        // inclusive scan across the wave
#pragma unroll
        for (int d = 1; d < 64; d <<= 1) {
            float n = __shfl_up(v, d, 64);
            if (lane >= d) v += n;
        }
        v += carry;
        if (j < IW) Ib[j] = v;
        carry = __shfl(v, 63, 64);
    }
}

// Thread per (batch, column); coalesced loads/stores down the rows.
__global__ __launch_bounds__(256) void integral_cols_kernel(float* __restrict__ I)
{
    const int t = blockIdx.x * 256 + threadIdx.x;
    if (t >= BN * IW) return;
    const int b = t / IW, j = t % IW;
    float* Ib = I + b * ISZ;
    float acc = 0.0f;
#pragma unroll 11
    for (int i = 1; i < IW; ++i) {
        acc += Ib[i * IW + j];
        Ib[i * IW + j] = acc;
    }
}

// One pixel per thread; consecutive lanes -> consecutive x => gather addresses
// stride 4 B/lane => ~4-5 cache lines per wave-load (vs 16 with 4px/thread).
__global__ __launch_bounds__(256) void bad_main_kernel(
    const float* __restrict__ I,
    const float* __restrict__ ox1, const float* __restrict__ ox2,
    const float* __restrict__ oy1, const float* __restrict__ oy2,
    const int*   __restrict__ radii, const float* __restrict__ thr,
    float* __restrict__ out)
{
    const int p = blockIdx.y;
    const int b = blockIdx.z;
    const int g = blockIdx.x * 256 + threadIdx.x;   // 0..50175 (196*256 exact)
    const int y = g / 224;
    const int x = g - y * 224;

    // block-uniform descriptor params -> scalar loads
    const float offx1 = ox1[p], offx2 = ox2[p];
    const float offy1 = oy1[p], offy2 = oy2[p];
    const int   rad   = radii[p];
    const float t     = thr[p];
    const float side  = (float)(2 * rad + 1);
    const float inv_area = 1.0f / (side * side);

    const float* Ib = I + b * ISZ;

    const float fy = (float)y;
    float fy1 = fminf(fmaxf(fy + offy1, 0.0f), (float)(HN - 1));
    int   cy1 = (int)fy1 + RN;
    const float* r1lo = Ib + (cy1 - rad) * IW;
    const float* r1hi = Ib + (cy1 + rad + 1) * IW;
    float fy2 = fminf(fmaxf(fy + offy2, 0.0f), (float)(HN - 1));
    int   cy2 = (int)fy2 + RN;
    const float* r2lo = Ib + (cy2 - rad) * IW;
    const float* r2hi = Ib + (cy2 + rad + 1) * IW;

    const float fx = (float)x;
    float fx1 = fminf(fmaxf(fx + offx1, 0.0f), (float)(WN - 1));
    int   cx1 = (int)fx1 + RN;
    int   a0 = cx1 - rad, a1 = cx1 + rad + 1;
    float s1 = r1hi[a1] - r1lo[a1] - r1hi[a0] + r1lo[a0];

    float fx2 = fminf(fmaxf(fx + offx2, 0.0f), (float)(WN - 1));
    int   cx2 = (int)fx2 + RN;
    int   b0 = cx2 - rad, b1 = cx2 + rad + 1;
    float s2 = r2hi[b1] - r2lo[b1] - r2hi[b0] + r2lo[b0];

    out[(b * PN + p) * NPIX + g] = (s1 - s2) * inv_area - t;
}

extern "C" void kernel_launch(void* const* d_in, const int* in_sizes, int n_in,
                              void* d_out, int out_size, void* d_ws, size_t ws_size,
                              hipStream_t stream)
{
    const float* x    = (const float*)d_in[0];
    const float* ox1  = (const float*)d_in[1];
    const float* ox2  = (const float*)d_in[2];
    const float* oy1  = (const float*)d_in[3];
    const float* oy2  = (const float*)d_in[4];
    const int*   rad  = (const int*)d_in[5];
    const float* thr  = (const float*)d_in[6];

    float* I   = (float*)d_ws;            // BN*ISZ floats = ~427 KB
    float* out = (float*)d_out;

    // 462 waves for rows: 462/4 waves-per-block -> 116 blocks
    hipLaunchKernelGGL(integral_rows_kernel, dim3((BN * IW * 64 + 255) / 256), dim3(256), 0, stream, x, I);
    hipLaunchKernelGGL(integral_cols_kernel, dim3((BN * IW + 255) / 256), dim3(256), 0, stream, I);
    hipLaunchKernelGGL(bad_main_kernel,      dim3(NPIX / 256, PN, BN), dim3(256), 0, stream,
                       I, ox1, ox2, oy1, oy2, rad, thr, out);
}